// Round 4
// baseline (76.274 us; speedup 1.0000x reference)
//
#include <hip/hip_runtime.h>
#include <hip/hip_bf16.h>

// SmoothLoss via LDS tiling.
// total = (1/24) * sum over 24 offsets of mean( exp(-||dx||^2/200) * ||dy||_1 ),
// x = rgb2ycbcr(input) (bias cancels in diffs), y = output.
// (dh,dw) ~ (-dh,-dw) pair up -> 12 representative offsets, weight 2x.
// Block = 256 threads stages a 10x132 tile (8x128 own + halo) of 6 planes
// (X0..X2 = ycbcr converted once, Y0..Y2 = output) into LDS, then each thread
// computes 4 pixels reading aligned 8-col windows via ds_read_b128.

#define B_ 16
#define H_ 512
#define W_ 512
#define HW_ (H_ * W_)
#define CHW_ (3 * HW_)

#define TW 128
#define TH 8
#define ROWS 10   // TH + 2 (bottom halo)
#define COLS 132  // TW + 4 (2 left + 2 right halo); image col j <-> lds idx j-jbase+2

__global__ void zero_out_kernel(float* p) { p[0] = 0.0f; }

template <int DH, int DW>
__device__ __forceinline__ float contrib(int j0, const float OX[3][8],
                                         const float OY[3][8],
                                         const float NX[3][8],
                                         const float NY[3][8]) {
  constexpr int AW = DW < 0 ? -DW : DW;
  const float scale =
      2.0f / (24.0f * (float)B_ * (float)(H_ - DH) * (float)(W_ - AW));
  float s = 0.0f;
#pragma unroll
  for (int p = 0; p < 4; ++p) {
    const int ci = p + 2;
    const int ni = p + DW + 2;
    float dx0 = OX[0][ci] - NX[0][ni];
    float dx1 = OX[1][ci] - NX[1][ni];
    float dx2 = OX[2][ci] - NX[2][ni];
    float wgt = __expf(-0.005f * (dx0 * dx0 + dx1 * dx1 + dx2 * dx2));
    float l1 = fabsf(OY[0][ci] - NY[0][ni]) + fabsf(OY[1][ci] - NY[1][ni]) +
               fabsf(OY[2][ci] - NY[2][ni]);
    int jj = j0 + p + DW;
    s += (jj >= 0 && jj < W_) ? scale * wgt * l1 : 0.0f;
  }
  return s;
}

__global__ __launch_bounds__(256) void smooth_loss_kernel(
    const float* __restrict__ in, const float* __restrict__ outp,
    float* __restrict__ result) {
  __shared__ float lds[6][ROWS][COLS];  // 31,680 B

  const int tid = threadIdx.x;
  const int bx = blockIdx.x;          // 0..3   (col tile)
  const int by = blockIdx.y;          // 0..63  (row tile)
  const int b = blockIdx.z;           // 0..15  (batch)
  const int jbase = bx * TW;
  const int ibase = by * TH;

  const float* inb = in + (size_t)b * CHW_;
  const float* outb = outp + (size_t)b * CHW_;

  // ---- staging: 340 items = 10 rows x 34 aligned float4 columns ----
  for (int item = tid; item < ROWS * 34; item += 256) {
    int r = item / 34;
    int c4 = item - r * 34;
    int ir = ibase + r;
    ir = ir < H_ - 1 ? ir : H_ - 1;              // clamp bottom (masked later)
    int gc = jbase + 4 * c4 - 4;                 // image col of this float4
    gc = gc < 0 ? 0 : (gc > W_ - 4 ? W_ - 4 : gc);  // clamp (masked later)
    const float* p = inb + (size_t)ir * W_ + gc;
    float4 rr = *(const float4*)(p);
    float4 gg = *(const float4*)(p + HW_);
    float4 bb = *(const float4*)(p + 2 * HW_);
    const float* q = outb + (size_t)ir * W_ + gc;
    float4 o0 = *(const float4*)(q);
    float4 o1 = *(const float4*)(q + HW_);
    float4 o2 = *(const float4*)(q + 2 * HW_);

    float rv[4] = {rr.x, rr.y, rr.z, rr.w};
    float gv[4] = {gg.x, gg.y, gg.z, gg.w};
    float bv[4] = {bb.x, bb.y, bb.z, bb.w};
    float x0[4], x1[4], x2[4];
#pragma unroll
    for (int c = 0; c < 4; ++c) {
      x0[c] = 0.257f * rv[c] + 0.564f * gv[c] + 0.098f * bv[c];
      x1[c] = -0.148f * rv[c] - 0.291f * gv[c] + 0.439f * bv[c];
      x2[c] = 0.439f * rv[c] - 0.368f * gv[c] - 0.071f * bv[c];
    }
    // lds float index of this float4's first element: 4*c4 - 2
    int fi = 4 * c4 - 2;
    if (c4 > 0) {  // write pair (elem 0,1) at fi (8B aligned)
      *(float2*)&lds[0][r][fi] = make_float2(x0[0], x0[1]);
      *(float2*)&lds[1][r][fi] = make_float2(x1[0], x1[1]);
      *(float2*)&lds[2][r][fi] = make_float2(x2[0], x2[1]);
      *(float2*)&lds[3][r][fi] = make_float2(o0.x, o0.y);
      *(float2*)&lds[4][r][fi] = make_float2(o1.x, o1.y);
      *(float2*)&lds[5][r][fi] = make_float2(o2.x, o2.y);
    }
    if (c4 < 33) {  // write pair (elem 2,3) at fi+2
      *(float2*)&lds[0][r][fi + 2] = make_float2(x0[2], x0[3]);
      *(float2*)&lds[1][r][fi + 2] = make_float2(x1[2], x1[3]);
      *(float2*)&lds[2][r][fi + 2] = make_float2(x2[2], x2[3]);
      *(float2*)&lds[3][r][fi + 2] = make_float2(o0.z, o0.w);
      *(float2*)&lds[4][r][fi + 2] = make_float2(o1.z, o1.w);
      *(float2*)&lds[5][r][fi + 2] = make_float2(o2.z, o2.w);
    }
  }

  __syncthreads();

  // ---- compute: thread -> (row rl, 4 px starting at col 4*jt) ----
  const int rl = tid >> 5;    // 0..7
  const int jt = tid & 31;    // 0..31
  const int i = ibase + rl;   // own image row, always < H_
  const int j0 = jbase + 4 * jt;
  const int fc = 4 * jt;      // lds float col of window start (j0-2)

  float OX[3][8], OY[3][8], NX[3][8], NY[3][8];

#pragma unroll
  for (int p = 0; p < 3; ++p) {
    *(float4*)&OX[p][0] = *(const float4*)&lds[p][rl][fc];
    *(float4*)&OX[p][4] = *(const float4*)&lds[p][rl][fc + 4];
    *(float4*)&OY[p][0] = *(const float4*)&lds[p + 3][rl][fc];
    *(float4*)&OY[p][4] = *(const float4*)&lds[p + 3][rl][fc + 4];
  }

  float acc = 0.0f;
  acc += contrib<0, 1>(j0, OX, OY, OX, OY);
  acc += contrib<0, 2>(j0, OX, OY, OX, OY);

#pragma unroll
  for (int p = 0; p < 3; ++p) {
    *(float4*)&NX[p][0] = *(const float4*)&lds[p][rl + 1][fc];
    *(float4*)&NX[p][4] = *(const float4*)&lds[p][rl + 1][fc + 4];
    *(float4*)&NY[p][0] = *(const float4*)&lds[p + 3][rl + 1][fc];
    *(float4*)&NY[p][4] = *(const float4*)&lds[p + 3][rl + 1][fc + 4];
  }
  if (i + 1 < H_) {
    acc += contrib<1, -2>(j0, OX, OY, NX, NY);
    acc += contrib<1, -1>(j0, OX, OY, NX, NY);
    acc += contrib<1, 0>(j0, OX, OY, NX, NY);
    acc += contrib<1, 1>(j0, OX, OY, NX, NY);
    acc += contrib<1, 2>(j0, OX, OY, NX, NY);
  }

#pragma unroll
  for (int p = 0; p < 3; ++p) {
    *(float4*)&NX[p][0] = *(const float4*)&lds[p][rl + 2][fc];
    *(float4*)&NX[p][4] = *(const float4*)&lds[p][rl + 2][fc + 4];
    *(float4*)&NY[p][0] = *(const float4*)&lds[p + 3][rl + 2][fc];
    *(float4*)&NY[p][4] = *(const float4*)&lds[p + 3][rl + 2][fc + 4];
  }
  if (i + 2 < H_) {
    acc += contrib<2, -2>(j0, OX, OY, NX, NY);
    acc += contrib<2, -1>(j0, OX, OY, NX, NY);
    acc += contrib<2, 0>(j0, OX, OY, NX, NY);
    acc += contrib<2, 1>(j0, OX, OY, NX, NY);
    acc += contrib<2, 2>(j0, OX, OY, NX, NY);
  }

  // ---- reduction ----
#pragma unroll
  for (int o = 32; o > 0; o >>= 1) acc += __shfl_down(acc, o, 64);

  __shared__ float wsum[4];
  int lane = tid & 63;
  int wid = tid >> 6;
  if (lane == 0) wsum[wid] = acc;
  __syncthreads();
  if (tid == 0) {
    float s = wsum[0] + wsum[1] + wsum[2] + wsum[3];
    atomicAdd(result, s);
  }
}

extern "C" void kernel_launch(void* const* d_in, const int* in_sizes, int n_in,
                              void* d_out, int out_size, void* d_ws, size_t ws_size,
                              hipStream_t stream) {
  const float* in = (const float*)d_in[0];
  const float* outp = (const float*)d_in[1];
  float* res = (float*)d_out;

  zero_out_kernel<<<1, 1, 0, stream>>>(res);

  dim3 grid(W_ / TW, H_ / TH, B_);  // (4, 64, 16)
  smooth_loss_kernel<<<grid, 256, 0, stream>>>(in, outp, res);
}

// Round 5
// 58.138 us; speedup vs baseline: 1.3120x; 1.3120x over previous
//
#include <hip/hip_runtime.h>
#include <hip/hip_bf16.h>
#include <stdint.h>

// SmoothLoss: total = (1/24) * sum over 24 offsets of mean( exp(-||dx||^2/200) * ||dy||_1 )
// x = rgb2ycbcr(input) (bias cancels in diffs), y = output.
// (dh,dw) ~ (-dh,-dw) pair -> 12 offsets, weight 2x.
// R4 structure:
//   - full-width row tile: 8 own rows + 2 halo rows x 520 cols (4+512+4) x 6 planes, fp32 LDS
//   - Phase A: global_load_lds staging (no VGPR landing -> deep MLP), 120 x 1KB chunks
//   - halo poisoning: X-halo = 1e19 => wgt = exp(-~1e38*k) = 0 => no bounds checks anywhere
//   - Phase B: in-place rgb->ycbcr, coefficients pre-scaled by sqrt(0.005) (exp arg needs no mul)
//   - Phase C: register windows via float2 LDS reads (16B lane stride, conflict-free),
//     12 compile-time offsets, 15 VALU ops per pixel-offset

#define B_ 16
#define H_ 512
#define W_ 512
#define HW_ (H_ * W_)
#define CHW_ (3 * HW_)

#define TH 8          // own rows per block
#define ROWS 10       // TH + 2 bottom halo
#define COLS 520      // 4 pad | 512 | 4 pad ; img col j <-> lds col j+4
#define NTHREADS 512
#define POISON 1e19f

__global__ void zero_out_kernel(float* p) { p[0] = 0.0f; }

__device__ __forceinline__ void gload16(const float* gsrc, float* ldst) {
  __builtin_amdgcn_global_load_lds(
      (const __attribute__((address_space(1))) void*)gsrc,
      (__attribute__((address_space(3))) void*)ldst, 16, 0, 0);
}

// O, N: [plane][window]; planes 0-2 = scaled ycbcr, 3-5 = out. window i <-> img col j0-2+i.
template <int DH, int DW>
__device__ __forceinline__ float contrib(const float (&O)[6][8], const float (&N)[6][8]) {
  constexpr int AW = DW < 0 ? -DW : DW;
  const float scale =
      2.0f / (24.0f * (float)B_ * (float)(H_ - DH) * (float)(W_ - AW));
  float s = 0.0f;
#pragma unroll
  for (int p = 0; p < 4; ++p) {
    const int ci = p + 2;
    const int ni = p + 2 + DW;
    float d0 = O[0][ci] - N[0][ni];
    float d1 = O[1][ci] - N[1][ni];
    float d2 = O[2][ci] - N[2][ni];
    float q = d0 * d0 + d1 * d1 + d2 * d2;   // already x0.005 via baked sqrt scale
    float wgt = __expf(-q);
    float l1 = fabsf(O[3][ci] - N[3][ni]) + fabsf(O[4][ci] - N[4][ni]) +
               fabsf(O[5][ci] - N[5][ni]);
    s += wgt * l1;
  }
  return scale * s;
}

__global__ __launch_bounds__(NTHREADS) void smooth_loss_kernel(
    const float* __restrict__ in, const float* __restrict__ outp,
    float* __restrict__ result) {
  __shared__ float lds[6][ROWS][COLS];   // 124,800 B
  __shared__ float wsum[NTHREADS / 64];

  const int tid = threadIdx.x;
  const int wv = tid >> 6;     // 0..7 (= own LDS row)
  const int lane = tid & 63;
  const int by = blockIdx.x;   // 0..63 row tile
  const int b = blockIdx.y;    // 0..15 batch
  const int ibase = by * TH;

  const float* inb = in + (size_t)b * CHW_;
  const float* outb = outp + (size_t)b * CHW_;

  // ---- Phase A: async stage. 120 chunks = 10 rows x 6 planes x 2 half-rows ----
#pragma unroll
  for (int k = 0; k < 15; ++k) {
    int c = wv + 8 * k;          // wave-uniform
    int r = c / 12;
    int rem = c - r * 12;
    int p = rem >> 1;
    int h = rem & 1;
    if (ibase + r < H_) {
      const float* src =
          (p < 3 ? inb + (size_t)p * HW_ : outb + (size_t)(p - 3) * HW_) +
          (size_t)(ibase + r) * W_ + 256 * h + 4 * lane;
      gload16(src, &lds[p][r][4 + 256 * h]);
    }
  }

  // ---- poison halo columns (all rows): plane0 = POISON, others = 0 ----
  if (tid < 480) {
    int p = tid / 80;
    int rr = (tid % 80) / 8;
    int ci = tid % 8;
    int col = ci < 4 ? ci : 512 + ci;
    lds[p][rr][col] = (p == 0) ? POISON : 0.0f;
  }
  // ---- poison bottom rows entirely for the last row tile ----
  if (ibase + TH >= H_) {
    for (int c = tid; c < 6 * 2 * 130; c += NTHREADS) {
      int p = c / 260;
      int rem = c - p * 260;
      int r = 8 + rem / 130;
      int q4 = rem % 130;
      float v = (p == 0) ? POISON : 0.0f;
      *(float4*)&lds[p][r][4 * q4] = make_float4(v, v, v, v);
    }
  }

  __syncthreads();  // drains gload_lds (vmcnt) + ds_writes

  // ---- Phase B: in-place rgb -> ycbcr, coefficients x sqrt(0.005) ----
  {
    const float K = 0.07071067811865475f;  // sqrt(0.005)
#pragma unroll
    for (int k = 0; k < 5; ++k) {
      int c = tid + NTHREADS * k;  // 0..2559 = 10 rows x 256 two-px chunks
      int r = c >> 8;
      int c2 = c & 255;
      if (ibase + r < H_) {
        int col = 4 + 2 * c2;
        float2 rr = *(const float2*)&lds[0][r][col];
        float2 gg = *(const float2*)&lds[1][r][col];
        float2 bb = *(const float2*)&lds[2][r][col];
        float2 x0, x1, x2;
        x0.x = (0.257f * K) * rr.x + (0.564f * K) * gg.x + (0.098f * K) * bb.x;
        x0.y = (0.257f * K) * rr.y + (0.564f * K) * gg.y + (0.098f * K) * bb.y;
        x1.x = (-0.148f * K) * rr.x + (-0.291f * K) * gg.x + (0.439f * K) * bb.x;
        x1.y = (-0.148f * K) * rr.y + (-0.291f * K) * gg.y + (0.439f * K) * bb.y;
        x2.x = (0.439f * K) * rr.x + (-0.368f * K) * gg.x + (-0.071f * K) * bb.x;
        x2.y = (0.439f * K) * rr.y + (-0.368f * K) * gg.y + (-0.071f * K) * bb.y;
        *(float2*)&lds[0][r][col] = x0;
        *(float2*)&lds[1][r][col] = x1;
        *(float2*)&lds[2][r][col] = x2;
      }
    }
  }

  __syncthreads();

  // ---- Phase C: window compute, 4 px per lane per group, 2 groups ----
  float acc = 0.0f;
#pragma unroll
  for (int g = 0; g < 2; ++g) {
    const int fc = 4 * lane + 256 * g + 2;  // lds col of window start (img j0-2)

    float O[6][8], N1[6][8], N2[6][8];
#pragma unroll
    for (int p = 0; p < 6; ++p) {
#pragma unroll
      for (int m = 0; m < 4; ++m)
        *(float2*)&O[p][2 * m] = *(const float2*)&lds[p][wv][fc + 2 * m];
    }
#pragma unroll
    for (int p = 0; p < 6; ++p) {
#pragma unroll
      for (int m = 0; m < 4; ++m)
        *(float2*)&N1[p][2 * m] = *(const float2*)&lds[p][wv + 1][fc + 2 * m];
    }
#pragma unroll
    for (int p = 0; p < 6; ++p) {
#pragma unroll
      for (int m = 0; m < 4; ++m)
        *(float2*)&N2[p][2 * m] = *(const float2*)&lds[p][wv + 2][fc + 2 * m];
    }

    acc += contrib<0, 1>(O, O);
    acc += contrib<0, 2>(O, O);
    acc += contrib<1, -2>(O, N1);
    acc += contrib<1, -1>(O, N1);
    acc += contrib<1, 0>(O, N1);
    acc += contrib<1, 1>(O, N1);
    acc += contrib<1, 2>(O, N1);
    acc += contrib<2, -2>(O, N2);
    acc += contrib<2, -1>(O, N2);
    acc += contrib<2, 0>(O, N2);
    acc += contrib<2, 1>(O, N2);
    acc += contrib<2, 2>(O, N2);
  }

  // ---- reduction ----
#pragma unroll
  for (int o = 32; o > 0; o >>= 1) acc += __shfl_down(acc, o, 64);
  if (lane == 0) wsum[wv] = acc;
  __syncthreads();
  if (tid == 0) {
    float s = 0.0f;
#pragma unroll
    for (int wq = 0; wq < NTHREADS / 64; ++wq) s += wsum[wq];
    atomicAdd(result, s);
  }
}

extern "C" void kernel_launch(void* const* d_in, const int* in_sizes, int n_in,
                              void* d_out, int out_size, void* d_ws, size_t ws_size,
                              hipStream_t stream) {
  const float* in = (const float*)d_in[0];
  const float* outp = (const float*)d_in[1];
  float* res = (float*)d_out;

  zero_out_kernel<<<1, 1, 0, stream>>>(res);

  dim3 grid(H_ / TH, B_, 1);  // (64, 16)
  smooth_loss_kernel<<<grid, NTHREADS, 0, stream>>>(in, outp, res);
}